// Round 11
// baseline (231.253 us; speedup 1.0000x reference)
//
#include <hip/hip_runtime.h>

// Problem: N=32, C=512, H=W=32 (HW=1024), D=256.
// out = x + b_fuse + (Z P^T)/rowsum ; Z = W_fuse * V, P = exp(Q K^T/16).
//
// Pipeline (all bf16 MFMA, fp32 accumulate), attention split into 2 pure GEMMs:
//  k_packw : weights -> bf16 ; zeros rowsumG
//  k_mm    : merged embed GEMM (tp = [theta|phi]) + Z GEMM, grid (256,4)  [r8 proven]
//  per half h (16 batches):
//   k_S  : P[nl][q][k] = exp(S/16) ; S = theta . phi^T  (K=256 GEMM, 128x128 tiles)
//          rowsum via LDS reduce + global atomicAdd into rowsumG
//   k_ZP : out[n][o][q] = x + b_fuse[o] + inv_rowsum[q] * sum_k Z[o,k] P[q,k]
//          (K=1024 GEMM, 128x128 tiles, both operands k-contiguous)
//
// P placement (no extra workspace):
//   h=0: P -> d_out bytes [32MB..64MB)  (out region of batches 16..31, untouched)
//   h=1: P -> ws [0..16MB) (tp batches 0-15, dead) + ws [32..48MB) (Z batches 0-15, dead)
// rowsumG: ws + 68157440 (32*1024 fp32 = 128 KB)
//
// Workspace: [0,32MB) tp ; [32,64MB) Z ; [64MiB,+512K) Wcat ; [+512K,+1MB) Wfuse ; +128K rowsumG

#define NB  32
#define CC  512
#define HWD 1024

typedef __attribute__((ext_vector_type(8))) short short8;
typedef __attribute__((ext_vector_type(4))) float f32x4;

__device__ __forceinline__ unsigned short f2bu(float f) {
    unsigned int u = __float_as_uint(f);
    u = (u + 0x7FFFu + ((u >> 16) & 1u)) >> 16;   // RNE to bf16
    return (unsigned short)u;
}

// ---------------- weights pack + rowsum zero ----------------
__global__ __launch_bounds__(256) void k_packw(const float* __restrict__ Wt,
                                               const float* __restrict__ Wp,
                                               const float* __restrict__ Wf,
                                               unsigned short* __restrict__ Wcat,
                                               unsigned short* __restrict__ Wfuse,
                                               float* __restrict__ rowsumG) {
    int idx = blockIdx.x * 256 + threadIdx.x;       // 0 .. 262143
    int o = idx >> 9;
    float cv = (o < 256) ? Wt[idx] : Wp[idx - 131072];
    Wcat[idx]  = f2bu(cv);
    Wfuse[idx] = f2bu(Wf[idx]);
    if (idx < 32768) rowsumG[idx] = 0.f;
}

// ---------------- merged GEMM: embed (y<2) / Z (y>=2) [r8 proven] ----------------
__global__ __launch_bounds__(512) void k_mm(const float* __restrict__ x,
                                            const unsigned short* __restrict__ Wcat,
                                            const unsigned short* __restrict__ Wfuse,
                                            const float* __restrict__ bt,
                                            const float* __restrict__ bp,
                                            unsigned short* __restrict__ tp,
                                            unsigned short* __restrict__ Z) {
    __shared__ __align__(16) float Tr[32 * 132];                 // 16896 B
    __shared__ __align__(16) unsigned short As[128 * 40];        // 10240 B
    __shared__ __align__(16) unsigned short Bs[256 * 40];        // 20480 B
    const int m0 = blockIdx.x << 7;
    const int yb = blockIdx.y;
    const bool isZ = (yb >= 2);
    const int n0 = (yb & 1) << 8;
    const unsigned short* W = isZ ? Wfuse : Wcat;
    const int n  = m0 >> 10, qbase = m0 & 1023;
    const int t = threadIdx.x, lane = t & 63, wave = t >> 6;
    const int wr = wave >> 2, wc = wave & 3;
    const int lrow = lane & 15, hi = lane >> 4, lhk = hi << 3;
    const f32x4 fz = {0.f, 0.f, 0.f, 0.f};
    f32x4 acc[4][4];
#pragma unroll
    for (int i = 0; i < 4; ++i)
#pragma unroll
        for (int j = 0; j < 4; ++j) acc[i][j] = fz;

    const int tr_r = t >> 4, tr_q = (t & 15) << 3;
    const int p2_pix = t & 127, p2_c = (t >> 7) << 3;

    for (int kt = 0; kt < 16; ++kt) {
        const int k0 = kt << 5;
        {
            const float* src = x + ((size_t)(n * CC + k0 + tr_r)) * HWD + qbase + tr_q;
            float4 v0 = *(const float4*)(src);
            float4 v1 = *(const float4*)(src + 4);
            *(float4*)(Tr + tr_r * 132 + tr_q) = v0;
            *(float4*)(Tr + tr_r * 132 + tr_q + 4) = v1;
#pragma unroll
            for (int i = 0; i < 2; ++i) {
                int chunk = t + (i << 9);
                int r = chunk >> 2, ko = (chunk & 3) << 3;
                *(uint4*)(Bs + r * 40 + ko) =
                    *(const uint4*)(W + ((size_t)(n0 + r)) * CC + k0 + ko);
            }
        }
        __syncthreads();
        {
            short8 o8;
#pragma unroll
            for (int j = 0; j < 8; ++j)
                o8[j] = (short)f2bu(Tr[(p2_c + j) * 132 + p2_pix]);
            *(short8*)(As + p2_pix * 40 + p2_c) = o8;
        }
        __syncthreads();
        short8 af[4], bfm[4];
#pragma unroll
        for (int mi = 0; mi < 4; ++mi)
            af[mi] = *(const short8*)(As + (wr * 64 + mi * 16 + lrow) * 40 + lhk);
#pragma unroll
        for (int ni = 0; ni < 4; ++ni)
            bfm[ni] = *(const short8*)(Bs + (wc * 64 + ni * 16 + lrow) * 40 + lhk);
#pragma unroll
        for (int mi = 0; mi < 4; ++mi)
#pragma unroll
            for (int ni = 0; ni < 4; ++ni)
                acc[mi][ni] = __builtin_amdgcn_mfma_f32_16x16x32_bf16(
                    af[mi], bfm[ni], acc[mi][ni], 0, 0, 0);
        __syncthreads();
    }
    if (!isZ) {
#pragma unroll
        for (int ni = 0; ni < 4; ++ni) {
            const int col = n0 + wc * 64 + ni * 16 + lrow;
            const float bias = (col < 256) ? bt[col] : bp[col - 256];
#pragma unroll
            for (int mi = 0; mi < 4; ++mi)
#pragma unroll
                for (int j = 0; j < 4; ++j) {
                    const int row = m0 + wr * 64 + mi * 16 + hi * 4 + j;
                    tp[(size_t)row * CC + col] = f2bu(acc[mi][ni][j] + bias);
                }
        }
    } else {
        const int kbase = qbase + wr * 64;
        unsigned short* Zn = Z + (size_t)n * CC * HWD;
#pragma unroll
        for (int ni = 0; ni < 4; ++ni) {
            const int o = n0 + wc * 64 + ni * 16 + lrow;
#pragma unroll
            for (int mi = 0; mi < 4; ++mi) {
                ushort4 v;
                v.x = f2bu(acc[mi][ni][0]);
                v.y = f2bu(acc[mi][ni][1]);
                v.z = f2bu(acc[mi][ni][2]);
                v.w = f2bu(acc[mi][ni][3]);
                *(ushort4*)(Zn + (size_t)o * HWD + kbase + mi * 16 + (hi << 2)) = v;
            }
        }
    }
}

// ---------------- k_S: P = exp(theta . phi^T / 16), rowsum atomics ----------------
// 256 threads, 128q x 128k tile, K=256 (8 steps). grid (8 q, 8 k, 16 n).
__global__ __launch_bounds__(256) void k_S(const unsigned short* __restrict__ tpH,
                                           unsigned short* __restrict__ Pb0,
                                           unsigned short* __restrict__ Pb1,
                                           float* __restrict__ rsH) {
    __shared__ __align__(16) unsigned short As[128 * 40];
    __shared__ __align__(16) unsigned short Bs[128 * 40];
    __shared__ float rs[128];
    const int m0 = blockIdx.x << 7;                // q tile
    const int k0b = blockIdx.y << 7;               // key tile
    const int nl = blockIdx.z;                     // 0..15
    const unsigned short* tpn = tpH + (size_t)nl * HWD * CC;
    unsigned short* Pn = (nl < 8) ? (Pb0 + (size_t)nl * HWD * HWD)
                                  : (Pb1 + (size_t)(nl - 8) * HWD * HWD);
    const int t = threadIdx.x, lane = t & 63, wave = t >> 6;
    const int wr = wave >> 1, wc = wave & 1;
    const int lrow = lane & 15, hi = lane >> 4, lhk = hi << 3;
    const f32x4 fz = {0.f, 0.f, 0.f, 0.f};
    f32x4 acc[4][4];
#pragma unroll
    for (int i = 0; i < 4; ++i)
#pragma unroll
        for (int j = 0; j < 4; ++j) acc[i][j] = fz;
    if (t < 128) rs[t] = 0.f;

    for (int kt = 0; kt < 8; ++kt) {               // K = 256 (d)
        const int k0 = kt << 5;
#pragma unroll
        for (int i = 0; i < 2; ++i) {
            int chunk = t + (i << 8);
            int r = chunk >> 2, ko = (chunk & 3) << 3;
            *(uint4*)(As + r * 40 + ko) =
                *(const uint4*)(tpn + (size_t)(m0 + r) * CC + k0 + ko);
            *(uint4*)(Bs + r * 40 + ko) =
                *(const uint4*)(tpn + (size_t)(k0b + r) * CC + 256 + k0 + ko);
        }
        __syncthreads();
        short8 af[4], bfm[4];
#pragma unroll
        for (int mi = 0; mi < 4; ++mi)
            af[mi] = *(const short8*)(As + (wr * 64 + mi * 16 + lrow) * 40 + lhk);
#pragma unroll
        for (int ni = 0; ni < 4; ++ni)
            bfm[ni] = *(const short8*)(Bs + (wc * 64 + ni * 16 + lrow) * 40 + lhk);
#pragma unroll
        for (int mi = 0; mi < 4; ++mi)
#pragma unroll
            for (int ni = 0; ni < 4; ++ni)
                acc[mi][ni] = __builtin_amdgcn_mfma_f32_16x16x32_bf16(
                    af[mi], bfm[ni], acc[mi][ni], 0, 0, 0);
        __syncthreads();
    }
    // epilogue: exp -> P store, rowsum reduce
    float sloc[4][4];
#pragma unroll
    for (int mi = 0; mi < 4; ++mi)
#pragma unroll
        for (int j = 0; j < 4; ++j) sloc[mi][j] = 0.f;
#pragma unroll
    for (int ni = 0; ni < 4; ++ni) {
        const int kc = k0b + wc * 64 + ni * 16 + lrow;
#pragma unroll
        for (int mi = 0; mi < 4; ++mi)
#pragma unroll
            for (int j = 0; j < 4; ++j) {
                const int row = m0 + wr * 64 + mi * 16 + hi * 4 + j;
                float p = __expf(acc[mi][ni][j] * 0.0625f);
                sloc[mi][j] += p;
                Pn[(size_t)row * HWD + kc] = f2bu(p);
            }
    }
#pragma unroll
    for (int mi = 0; mi < 4; ++mi)
#pragma unroll
        for (int j = 0; j < 4; ++j) {
            float s = sloc[mi][j];
            s += __shfl_xor(s, 1, 16);
            s += __shfl_xor(s, 2, 16);
            s += __shfl_xor(s, 4, 16);
            s += __shfl_xor(s, 8, 16);
            if (lrow == 0) atomicAdd(&rs[wr * 64 + mi * 16 + hi * 4 + j], s);
        }
    __syncthreads();
    if (t < 128) atomicAdd(&rsH[(size_t)nl * HWD + m0 + t], rs[t]);
}

// ---------------- k_ZP: out = x + b + inv_rowsum * (Z . P^T) ----------------
// 256 threads, 128o x 128q tile, K=1024 (32 steps). grid (8 q, 4 o, 16 n).
__global__ __launch_bounds__(256) void k_ZP(const unsigned short* __restrict__ ZH,
                                            const unsigned short* __restrict__ Pb0,
                                            const unsigned short* __restrict__ Pb1,
                                            const float* __restrict__ rsH,
                                            const float* __restrict__ bfu,
                                            const float* __restrict__ xH,
                                            float* __restrict__ outH) {
    __shared__ __align__(16) unsigned short As[128 * 40];
    __shared__ __align__(16) unsigned short Bs[128 * 40];
    const int q0 = blockIdx.x << 7;                // q tile
    const int o0 = blockIdx.y << 7;                // o tile
    const int nl = blockIdx.z;                     // 0..15
    const unsigned short* Zn = ZH + (size_t)nl * CC * HWD;
    const unsigned short* Pn = (nl < 8) ? (Pb0 + (size_t)nl * HWD * HWD)
                                        : (Pb1 + (size_t)(nl - 8) * HWD * HWD);
    const int t = threadIdx.x, lane = t & 63, wave = t >> 6;
    const int wr = wave >> 1, wc = wave & 1;
    const int lrow = lane & 15, hi = lane >> 4, lhk = hi << 3;
    const f32x4 fz = {0.f, 0.f, 0.f, 0.f};
    f32x4 acc[4][4];                               // row=o, col=q
#pragma unroll
    for (int i = 0; i < 4; ++i)
#pragma unroll
        for (int j = 0; j < 4; ++j) acc[i][j] = fz;

    for (int kt = 0; kt < 32; ++kt) {              // K = 1024 (keys)
        const int k0 = kt << 5;
#pragma unroll
        for (int i = 0; i < 2; ++i) {
            int chunk = t + (i << 8);
            int r = chunk >> 2, ko = (chunk & 3) << 3;
            *(uint4*)(As + r * 40 + ko) =
                *(const uint4*)(Zn + (size_t)(o0 + r) * HWD + k0 + ko);
            *(uint4*)(Bs + r * 40 + ko) =
                *(const uint4*)(Pn + (size_t)(q0 + r) * HWD + k0 + ko);
        }
        __syncthreads();
        short8 af[4], bfm[4];
#pragma unroll
        for (int mi = 0; mi < 4; ++mi)
            af[mi] = *(const short8*)(As + (wr * 64 + mi * 16 + lrow) * 40 + lhk);
#pragma unroll
        for (int ni = 0; ni < 4; ++ni)
            bfm[ni] = *(const short8*)(Bs + (wc * 64 + ni * 16 + lrow) * 40 + lhk);
#pragma unroll
        for (int mi = 0; mi < 4; ++mi)
#pragma unroll
            for (int ni = 0; ni < 4; ++ni)
                acc[mi][ni] = __builtin_amdgcn_mfma_f32_16x16x32_bf16(
                    af[mi], bfm[ni], acc[mi][ni], 0, 0, 0);
        __syncthreads();
    }
    // epilogue: divide by rowsum, add bias + residual
#pragma unroll
    for (int ni = 0; ni < 4; ++ni) {
        const int qc = q0 + wc * 64 + ni * 16 + lrow;
        const float inv = 1.f / rsH[(size_t)nl * HWD + qc];
#pragma unroll
        for (int mi = 0; mi < 4; ++mi)
#pragma unroll
            for (int j = 0; j < 4; ++j) {
                const int o = o0 + wr * 64 + mi * 16 + hi * 4 + j;
                const size_t idx = ((size_t)(nl * CC + o)) * HWD + qc;
                outH[idx] = acc[mi][ni][j] * inv + bfu[o] + xH[idx];
            }
    }
}

extern "C" void kernel_launch(void* const* d_in, const int* in_sizes, int n_in,
                              void* d_out, int out_size, void* d_ws, size_t ws_size,
                              hipStream_t stream) {
    const float* x  = (const float*)d_in[0];
    const float* Wt = (const float*)d_in[1];
    const float* bt = (const float*)d_in[2];
    const float* Wp = (const float*)d_in[3];
    const float* bp = (const float*)d_in[4];
    const float* Wf = (const float*)d_in[5];
    const float* bfu = (const float*)d_in[6];
    float* out = (float*)d_out;

    char* ws = (char*)d_ws;
    unsigned short* tp    = (unsigned short*)(ws);                 // 32 MB
    unsigned short* Z     = (unsigned short*)(ws + 33554432);      // 32 MB
    unsigned short* Wcat  = (unsigned short*)(ws + 67108864);      // 512 KB
    unsigned short* Wfuse = (unsigned short*)(ws + 67633152);      // 512 KB
    float*          rsG   = (float*)(ws + 68157440);               // 128 KB

    const size_t HB = (size_t)16 * HWD * CC;       // elems per 16-batch half (tp/Z)

    k_packw<<<dim3(1024), 256, 0, stream>>>(Wt, Wp, Wf, Wcat, Wfuse, rsG);
    k_mm   <<<dim3(256, 4), 512, 0, stream>>>(x, Wcat, Wfuse, bt, bp, tp, Z);

    // half 0 (batches 0..15): P -> d_out upper 32 MB (out region of batches 16..31)
    {
        unsigned short* P0 = (unsigned short*)(out + (size_t)8 * 1024 * 1024);
        unsigned short* P0b = P0 + (size_t)8 * HWD * HWD;
        k_S <<<dim3(8, 8, 16), 256, 0, stream>>>(tp, P0, P0b, rsG);
        k_ZP<<<dim3(8, 4, 16), 256, 0, stream>>>(Z, P0, P0b, rsG, bfu, x, out);
    }
    // half 1 (batches 16..31): P -> ws [0..16MB) (dead tp) + ws [32..48MB) (dead Z)
    {
        unsigned short* P1a = (unsigned short*)(ws);
        unsigned short* P1b = (unsigned short*)(ws + 33554432);
        k_S <<<dim3(8, 8, 16), 256, 0, stream>>>(tp + HB, P1a, P1b, rsG + 16 * HWD);
        k_ZP<<<dim3(8, 4, 16), 256, 0, stream>>>(Z + HB, P1a, P1b, rsG + 16 * HWD,
                                                 bfu, x + (size_t)16 * CC * HWD,
                                                 out + (size_t)16 * CC * HWD);
    }
}

// Round 12
// 181.314 us; speedup vs baseline: 1.2754x; 1.2754x over previous
//
#include <hip/hip_runtime.h>

// Problem: N=32, C=512, H=W=32 (HW=1024), D=256.
// out = x + b_fuse + (Z P^T)/rowsum ; Z = W_fuse * V, P = exp(Q K^T/16).
//
// Pipeline:
//  k_packw  : weights -> bf16
//  k_mm     : merged embed GEMM (tp = [theta|phi]) + Z GEMM, grid (256,4)  [r8 proven]
//  k_attn10 : r8's k_attn8 (q-tile 128, 8 waves, 1 block/CU, 4 iters of 256 keys,
//             per-iter psum fold -- register budget EXACTLY at the 256 ceiling,
//             do not add persistent state) with ONE change: raw s_barrier +
//             lgkmcnt-only waits (LBAR) instead of __syncthreads, so kf/zf
//             global loads stay in flight across barriers; kpre (next-iter K)
//             and zpre (first Z frag) issued under the previous MFMA cluster.
//             r9 regressed from REGISTER SPILLS (persistent psum pushed peak
//             >256), not from this discipline -- this isolates it.
//
// Workspace (65 MB): [0,32MB) tp ; [32,64MB) Z ; [64MB,+512K) Wcat ; [+512K,+1MB) Wfuse

#define NB  32
#define CC  512
#define HWD 1024

typedef __attribute__((ext_vector_type(8))) short short8;
typedef __attribute__((ext_vector_type(4))) float f32x4;

// LDS-only barrier: drain LDS ops, raw barrier, pin scheduling. Global loads
// (kpre/zpre) remain in flight across it.
#define LBAR() do {                                            \
    asm volatile("s_waitcnt lgkmcnt(0)" ::: "memory");         \
    __builtin_amdgcn_s_barrier();                              \
    __builtin_amdgcn_sched_barrier(0);                         \
} while (0)

__device__ __forceinline__ unsigned short f2bu(float f) {
    unsigned int u = __float_as_uint(f);
    u = (u + 0x7FFFu + ((u >> 16) & 1u)) >> 16;   // RNE to bf16
    return (unsigned short)u;
}

// ---------------- weights pack ----------------
__global__ __launch_bounds__(256) void k_packw(const float* __restrict__ Wt,
                                               const float* __restrict__ Wp,
                                               const float* __restrict__ Wf,
                                               unsigned short* __restrict__ Wcat,
                                               unsigned short* __restrict__ Wfuse) {
    int idx = blockIdx.x * 256 + threadIdx.x;       // 0 .. 262143
    int o = idx >> 9;
    float cv = (o < 256) ? Wt[idx] : Wp[idx - 131072];
    Wcat[idx]  = f2bu(cv);
    Wfuse[idx] = f2bu(Wf[idx]);
}

// ---------------- merged GEMM: embed (y<2) / Z (y>=2) [r8 proven] ----------------
__global__ __launch_bounds__(512) void k_mm(const float* __restrict__ x,
                                            const unsigned short* __restrict__ Wcat,
                                            const unsigned short* __restrict__ Wfuse,
                                            const float* __restrict__ bt,
                                            const float* __restrict__ bp,
                                            unsigned short* __restrict__ tp,
                                            unsigned short* __restrict__ Z) {
    __shared__ __align__(16) float Tr[32 * 132];                 // 16896 B
    __shared__ __align__(16) unsigned short As[128 * 40];        // 10240 B
    __shared__ __align__(16) unsigned short Bs[256 * 40];        // 20480 B
    const int m0 = blockIdx.x << 7;
    const int yb = blockIdx.y;
    const bool isZ = (yb >= 2);
    const int n0 = (yb & 1) << 8;
    const unsigned short* W = isZ ? Wfuse : Wcat;
    const int n  = m0 >> 10, qbase = m0 & 1023;
    const int t = threadIdx.x, lane = t & 63, wave = t >> 6;
    const int wr = wave >> 2, wc = wave & 3;
    const int lrow = lane & 15, hi = lane >> 4, lhk = hi << 3;
    const f32x4 fz = {0.f, 0.f, 0.f, 0.f};
    f32x4 acc[4][4];
#pragma unroll
    for (int i = 0; i < 4; ++i)
#pragma unroll
        for (int j = 0; j < 4; ++j) acc[i][j] = fz;

    const int tr_r = t >> 4, tr_q = (t & 15) << 3;
    const int p2_pix = t & 127, p2_c = (t >> 7) << 3;

    for (int kt = 0; kt < 16; ++kt) {
        const int k0 = kt << 5;
        {
            const float* src = x + ((size_t)(n * CC + k0 + tr_r)) * HWD + qbase + tr_q;
            float4 v0 = *(const float4*)(src);
            float4 v1 = *(const float4*)(src + 4);
            *(float4*)(Tr + tr_r * 132 + tr_q) = v0;
            *(float4*)(Tr + tr_r * 132 + tr_q + 4) = v1;
#pragma unroll
            for (int i = 0; i < 2; ++i) {
                int chunk = t + (i << 9);
                int r = chunk >> 2, ko = (chunk & 3) << 3;
                *(uint4*)(Bs + r * 40 + ko) =
                    *(const uint4*)(W + ((size_t)(n0 + r)) * CC + k0 + ko);
            }
        }
        __syncthreads();
        {
            short8 o8;
#pragma unroll
            for (int j = 0; j < 8; ++j)
                o8[j] = (short)f2bu(Tr[(p2_c + j) * 132 + p2_pix]);
            *(short8*)(As + p2_pix * 40 + p2_c) = o8;
        }
        __syncthreads();
        short8 af[4], bfm[4];
#pragma unroll
        for (int mi = 0; mi < 4; ++mi)
            af[mi] = *(const short8*)(As + (wr * 64 + mi * 16 + lrow) * 40 + lhk);
#pragma unroll
        for (int ni = 0; ni < 4; ++ni)
            bfm[ni] = *(const short8*)(Bs + (wc * 64 + ni * 16 + lrow) * 40 + lhk);
#pragma unroll
        for (int mi = 0; mi < 4; ++mi)
#pragma unroll
            for (int ni = 0; ni < 4; ++ni)
                acc[mi][ni] = __builtin_amdgcn_mfma_f32_16x16x32_bf16(
                    af[mi], bfm[ni], acc[mi][ni], 0, 0, 0);
        __syncthreads();
    }
    if (!isZ) {
#pragma unroll
        for (int ni = 0; ni < 4; ++ni) {
            const int col = n0 + wc * 64 + ni * 16 + lrow;
            const float bias = (col < 256) ? bt[col] : bp[col - 256];
#pragma unroll
            for (int mi = 0; mi < 4; ++mi)
#pragma unroll
                for (int j = 0; j < 4; ++j) {
                    const int row = m0 + wr * 64 + mi * 16 + hi * 4 + j;
                    tp[(size_t)row * CC + col] = f2bu(acc[mi][ni][j] + bias);
                }
        }
    } else {
        const int kbase = qbase + wr * 64;
        unsigned short* Zn = Z + (size_t)n * CC * HWD;
#pragma unroll
        for (int ni = 0; ni < 4; ++ni) {
            const int o = n0 + wc * 64 + ni * 16 + lrow;
#pragma unroll
            for (int mi = 0; mi < 4; ++mi) {
                ushort4 v;
                v.x = f2bu(acc[mi][ni][0]);
                v.y = f2bu(acc[mi][ni][1]);
                v.z = f2bu(acc[mi][ni][2]);
                v.w = f2bu(acc[mi][ni][3]);
                *(ushort4*)(Zn + (size_t)o * HWD + kbase + mi * 16 + (hi << 2)) = v;
            }
        }
    }
}

// ---------------- attention: out = x + b + (Z P^T)/rowsum ----------------
// 8 waves, 128-query tile, 4 iters of 256 keys, 256 blocks = 1/CU.
__global__ __launch_bounds__(512, 2) void k_attn10(const unsigned short* __restrict__ tp,
                                                   const unsigned short* __restrict__ Z,
                                                   const float* __restrict__ bfu,
                                                   const float* __restrict__ x,
                                                   float* __restrict__ out) {
    constexpr int QST = 264;
    constexpr int PST = 264;
    constexpr int QSZ = 128 * QST;
    __shared__ __align__(16) unsigned short SL[QSZ + 128 * PST];  // 135,168 B
    __shared__ float rowsum[128];
    unsigned short* Qs = SL;                       // [128][264]
    unsigned short* P  = SL + QSZ;                 // [128][264]

    const int b = blockIdx.x;
    const int n = b & 31;                          // XCD = n % 8
    const int q0 = (b >> 5) << 7;
    const int t = threadIdx.x, lane = t & 63, wave = t >> 6;
    const int lrow = lane & 15, hi = lane >> 4, lhk = hi << 3;
    const f32x4 fz = {0.f, 0.f, 0.f, 0.f};

    const unsigned short* tpn = tp + (size_t)n * HWD * CC;
    const unsigned short* Zn  = Z + (size_t)n * CC * HWD;

    if (t < 128) rowsum[t] = 0.f;
#pragma unroll
    for (int pass = 0; pass < 8; ++pass) {
        int chunk = (pass << 9) + t;
        int row = chunk >> 5, co = (chunk & 31) << 3;
        *(short8*)(Qs + row * QST + co) =
            *(const short8*)(tpn + (size_t)(q0 + row) * CC + co);
    }
    LBAR();

    f32x4 accG[8][4];
#pragma unroll
    for (int qj = 0; qj < 8; ++qj)
#pragma unroll
        for (int mi = 0; mi < 4; ++mi) accG[qj][mi] = fz;

    const int kw = wave << 4;
    const int ob = wave << 6;

    // prologue: prefetch kf (kt 0,1) for iter 0
    short8 kpre[2][2];
    {
        const size_t kr0 = (size_t)(kw + lrow) * CC + 256;
        const size_t kr1 = (size_t)(128 + kw + lrow) * CC + 256;
        kpre[0][0] = *(const short8*)(tpn + kr0 + lhk);
        kpre[0][1] = *(const short8*)(tpn + kr1 + lhk);
        kpre[1][0] = *(const short8*)(tpn + kr0 + 32 + lhk);
        kpre[1][1] = *(const short8*)(tpn + kr1 + 32 + lhk);
    }

    for (int it = 0; it < 4; ++it) {
        const int kv0 = it << 8;
        const size_t krow0 = (size_t)(kv0 + kw + lrow) * CC + 256;
        const size_t krow1 = (size_t)(kv0 + 128 + kw + lrow) * CC + 256;
        // ---- S phase ----
        f32x4 accA[2][8];
#pragma unroll
        for (int k2 = 0; k2 < 2; ++k2)
#pragma unroll
            for (int qj = 0; qj < 8; ++qj) accA[k2][qj] = fz;
#pragma unroll
        for (int kt = 0; kt < 8; ++kt) {
            const int d0 = (kt << 5) + lhk;
            short8 kf0, kf1;
            if (kt < 2) { kf0 = kpre[kt][0]; kf1 = kpre[kt][1]; }
            else {
                kf0 = *(const short8*)(tpn + krow0 + d0);
                kf1 = *(const short8*)(tpn + krow1 + d0);
            }
#pragma unroll
            for (int qj = 0; qj < 8; ++qj) {
                short8 qfr = *(const short8*)(Qs + (qj * 16 + lrow) * QST + d0);
                accA[0][qj] = __builtin_amdgcn_mfma_f32_16x16x32_bf16(qfr, kf0, accA[0][qj], 0, 0, 0);
                accA[1][qj] = __builtin_amdgcn_mfma_f32_16x16x32_bf16(qfr, kf1, accA[1][qj], 0, 0, 0);
            }
        }
        // exp -> P, psum per-iter (transient) + immediate fold [r8 register budget]
        {
            float psum[8][4];
#pragma unroll
            for (int qj = 0; qj < 8; ++qj)
#pragma unroll
                for (int j = 0; j < 4; ++j) psum[qj][j] = 0.f;
#pragma unroll
            for (int k2 = 0; k2 < 2; ++k2) {
                const int pcol = (k2 << 7) + kw + lrow;
#pragma unroll
                for (int qj = 0; qj < 8; ++qj)
#pragma unroll
                    for (int j = 0; j < 4; ++j) {
                        float p = __expf(accA[k2][qj][j] * 0.0625f);
                        psum[qj][j] += p;
                        P[(qj * 16 + hi * 4 + j) * PST + pcol] = f2bu(p);
                    }
            }
#pragma unroll
            for (int qj = 0; qj < 8; ++qj)
#pragma unroll
                for (int j = 0; j < 4; ++j) {
                    float s = psum[qj][j];
                    s += __shfl_xor(s, 1, 16);
                    s += __shfl_xor(s, 2, 16);
                    s += __shfl_xor(s, 4, 16);
                    s += __shfl_xor(s, 8, 16);
                    if (lrow == 0) atomicAdd(&rowsum[qj * 16 + hi * 4 + j], s);
                }
        }
        // prefetch zf(ks=0) — stays in flight across the barrier
        short8 zpre[4];
#pragma unroll
        for (int mi = 0; mi < 4; ++mi)
            zpre[mi] = *(const short8*)(Zn + (size_t)(ob + mi * 16 + lrow) * HWD + kv0 + lhk);
        LBAR();                                    // P visible (LDS-only drain)
        // prefetch kf (kt 0,1) of next iter — hidden under ZP MFMAs
        if (it < 3) {
            const size_t nr0 = (size_t)(kv0 + 256 + kw + lrow) * CC + 256;
            const size_t nr1 = (size_t)(kv0 + 384 + kw + lrow) * CC + 256;
            kpre[0][0] = *(const short8*)(tpn + nr0 + lhk);
            kpre[0][1] = *(const short8*)(tpn + nr1 + lhk);
            kpre[1][0] = *(const short8*)(tpn + nr0 + 32 + lhk);
            kpre[1][1] = *(const short8*)(tpn + nr1 + 32 + lhk);
        }
        // ---- ZP phase: accG[q][o] += P . Z^T ----
        __builtin_amdgcn_s_setprio(1);
#pragma unroll
        for (int ks = 0; ks < 8; ++ks) {
            const int kb = (ks << 5) + lhk;
            short8 zf[4];
            if (ks == 0) {
#pragma unroll
                for (int mi = 0; mi < 4; ++mi) zf[mi] = zpre[mi];
            } else {
#pragma unroll
                for (int mi = 0; mi < 4; ++mi)
                    zf[mi] = *(const short8*)(Zn + (size_t)(ob + mi * 16 + lrow) * HWD + kv0 + kb);
            }
#pragma unroll
            for (int qj = 0; qj < 8; ++qj) {
                short8 pa = *(const short8*)(P + (qj * 16 + lrow) * PST + kb);
#pragma unroll
                for (int mi = 0; mi < 4; ++mi)
                    accG[qj][mi] = __builtin_amdgcn_mfma_f32_16x16x32_bf16(
                        pa, zf[mi], accG[qj][mi], 0, 0, 0);
            }
        }
        __builtin_amdgcn_s_setprio(0);
        LBAR();                                    // P consumed; safe to overwrite
    }

    // ---- epilogue ----
    if (t < 128) rowsum[t] = 1.f / rowsum[t];
    LBAR();
    float bias[4];
#pragma unroll
    for (int mi = 0; mi < 4; ++mi) bias[mi] = bfu[ob + mi * 16 + lrow];
#pragma unroll
    for (int qj = 0; qj < 8; ++qj) {
        const float4 inv4 = *(const float4*)&rowsum[qj * 16 + (hi << 2)];
#pragma unroll
        for (int mi = 0; mi < 4; ++mi) {
            const int o = ob + mi * 16 + lrow;
            const size_t idx = ((size_t)(n * CC + o)) * HWD + q0 + qj * 16 + (hi << 2);
            const float4 xr = *(const float4*)(x + idx);
            float4 r;
            r.x = accG[qj][mi][0] * inv4.x + bias[mi] + xr.x;
            r.y = accG[qj][mi][1] * inv4.y + bias[mi] + xr.y;
            r.z = accG[qj][mi][2] * inv4.z + bias[mi] + xr.z;
            r.w = accG[qj][mi][3] * inv4.w + bias[mi] + xr.w;
            *(float4*)(out + idx) = r;
        }
    }
}

extern "C" void kernel_launch(void* const* d_in, const int* in_sizes, int n_in,
                              void* d_out, int out_size, void* d_ws, size_t ws_size,
                              hipStream_t stream) {
    const float* x  = (const float*)d_in[0];
    const float* Wt = (const float*)d_in[1];
    const float* bt = (const float*)d_in[2];
    const float* Wp = (const float*)d_in[3];
    const float* bp = (const float*)d_in[4];
    const float* Wf = (const float*)d_in[5];
    const float* bfu = (const float*)d_in[6];
    float* out = (float*)d_out;

    char* ws = (char*)d_ws;
    unsigned short* tp    = (unsigned short*)(ws);                 // 32 MB
    unsigned short* Z     = (unsigned short*)(ws + 33554432);      // 32 MB
    unsigned short* Wcat  = (unsigned short*)(ws + 67108864);      // 512 KB
    unsigned short* Wfuse = (unsigned short*)(ws + 67633152);      // 512 KB

    k_packw <<<dim3(1024), 256, 0, stream>>>(Wt, Wp, Wf, Wcat, Wfuse);
    k_mm    <<<dim3(256, 4), 512, 0, stream>>>(x, Wcat, Wfuse, bt, bp, tp, Z);
    k_attn10<<<dim3(256), 512, 0, stream>>>(tp, Z, bfu, x, out);
}

// Round 13
// 170.449 us; speedup vs baseline: 1.3567x; 1.0637x over previous
//
#include <hip/hip_runtime.h>

// Problem: N=32, C=512, H=W=32 (HW=1024), D=256.
// out = x + b_fuse + (Z P^T)/rowsum ; Z = W_fuse * V, P = exp(Q K^T/16).
//
// Pipeline:
//  k_packw : weights -> bf16
//  k_mm    : merged embed GEMM (tp = [theta|phi]) + Z GEMM, grid (256,4)
//  k_attn8 : per (n, 128-query tile), 8 waves, 256 blocks (exactly 1/CU).
//            4 iters of 256 keys: S phase (both 128-key subtiles per pass,
//            kfr pair loaded once per kt, qfr reused x2, accA[2][8]) -> P LDS
//            [128][264]; ZP phase swapped-operand mfma(pa, zf) -> accG[8][4]
//            (q-major output -> float4 stores + residual loads).
//            [locked r8 config: best of rounds 0-12 at 170.5us total.
//             Falsified alternatives: q64 tiles (r5/r6/r7), register prefetch
//             (r7), LBAR barrier discipline (r12), persistent psum (r9 spills),
//             dual-acc k_mm fusion (r10), split S/ZP GEMMs (r11).]
//
// Workspace (65 MB): [0,32MB) tp ; [32,64MB) Z ; [64MB,+512K) Wcat ; [+512K,+1MB) Wfuse

#define NB  32
#define CC  512
#define HWD 1024

typedef __attribute__((ext_vector_type(8))) short short8;
typedef __attribute__((ext_vector_type(4))) float f32x4;

__device__ __forceinline__ unsigned short f2bu(float f) {
    unsigned int u = __float_as_uint(f);
    u = (u + 0x7FFFu + ((u >> 16) & 1u)) >> 16;   // RNE to bf16
    return (unsigned short)u;
}

// ---------------- weights pack ----------------
__global__ __launch_bounds__(256) void k_packw(const float* __restrict__ Wt,
                                               const float* __restrict__ Wp,
                                               const float* __restrict__ Wf,
                                               unsigned short* __restrict__ Wcat,
                                               unsigned short* __restrict__ Wfuse) {
    int idx = blockIdx.x * 256 + threadIdx.x;       // 0 .. 262143
    int o = idx >> 9;
    float cv = (o < 256) ? Wt[idx] : Wp[idx - 131072];
    Wcat[idx]  = f2bu(cv);
    Wfuse[idx] = f2bu(Wf[idx]);
}

// ---------------- merged GEMM: embed (y<2) / Z (y>=2) ----------------
// M-tile 128 pixels (transpose-staged from fp32 x), N-tile 256.
__global__ __launch_bounds__(512) void k_mm(const float* __restrict__ x,
                                            const unsigned short* __restrict__ Wcat,
                                            const unsigned short* __restrict__ Wfuse,
                                            const float* __restrict__ bt,
                                            const float* __restrict__ bp,
                                            unsigned short* __restrict__ tp,
                                            unsigned short* __restrict__ Z) {
    __shared__ __align__(16) float Tr[32 * 132];                 // 16896 B
    __shared__ __align__(16) unsigned short As[128 * 40];        // 10240 B
    __shared__ __align__(16) unsigned short Bs[256 * 40];        // 20480 B
    const int m0 = blockIdx.x << 7;                // global pixel row base
    const int yb = blockIdx.y;
    const bool isZ = (yb >= 2);
    const int n0 = (yb & 1) << 8;                  // col base (0 or 256)
    const unsigned short* W = isZ ? Wfuse : Wcat;
    const int n  = m0 >> 10, qbase = m0 & 1023;
    const int t = threadIdx.x, lane = t & 63, wave = t >> 6;
    const int wr = wave >> 2, wc = wave & 3;
    const int lrow = lane & 15, hi = lane >> 4, lhk = hi << 3;
    const f32x4 fz = {0.f, 0.f, 0.f, 0.f};
    f32x4 acc[4][4];
#pragma unroll
    for (int i = 0; i < 4; ++i)
#pragma unroll
        for (int j = 0; j < 4; ++j) acc[i][j] = fz;

    const int tr_r = t >> 4, tr_q = (t & 15) << 3;        // Tr stage
    const int p2_pix = t & 127, p2_c = (t >> 7) << 3;     // transpose

    for (int kt = 0; kt < 16; ++kt) {
        const int k0 = kt << 5;
        {
            const float* src = x + ((size_t)(n * CC + k0 + tr_r)) * HWD + qbase + tr_q;
            float4 v0 = *(const float4*)(src);
            float4 v1 = *(const float4*)(src + 4);
            *(float4*)(Tr + tr_r * 132 + tr_q) = v0;
            *(float4*)(Tr + tr_r * 132 + tr_q + 4) = v1;
#pragma unroll
            for (int i = 0; i < 2; ++i) {
                int chunk = t + (i << 9);
                int r = chunk >> 2, ko = (chunk & 3) << 3;
                *(uint4*)(Bs + r * 40 + ko) =
                    *(const uint4*)(W + ((size_t)(n0 + r)) * CC + k0 + ko);
            }
        }
        __syncthreads();
        {
            short8 o8;
#pragma unroll
            for (int j = 0; j < 8; ++j)
                o8[j] = (short)f2bu(Tr[(p2_c + j) * 132 + p2_pix]);
            *(short8*)(As + p2_pix * 40 + p2_c) = o8;
        }
        __syncthreads();
        short8 af[4], bfm[4];
#pragma unroll
        for (int mi = 0; mi < 4; ++mi)
            af[mi] = *(const short8*)(As + (wr * 64 + mi * 16 + lrow) * 40 + lhk);
#pragma unroll
        for (int ni = 0; ni < 4; ++ni)
            bfm[ni] = *(const short8*)(Bs + (wc * 64 + ni * 16 + lrow) * 40 + lhk);
#pragma unroll
        for (int mi = 0; mi < 4; ++mi)
#pragma unroll
            for (int ni = 0; ni < 4; ++ni)
                acc[mi][ni] = __builtin_amdgcn_mfma_f32_16x16x32_bf16(
                    af[mi], bfm[ni], acc[mi][ni], 0, 0, 0);
        __syncthreads();
    }
    if (!isZ) {
#pragma unroll
        for (int ni = 0; ni < 4; ++ni) {
            const int col = n0 + wc * 64 + ni * 16 + lrow;
            const float bias = (col < 256) ? bt[col] : bp[col - 256];
#pragma unroll
            for (int mi = 0; mi < 4; ++mi)
#pragma unroll
                for (int j = 0; j < 4; ++j) {
                    const int row = m0 + wr * 64 + mi * 16 + hi * 4 + j;
                    tp[(size_t)row * CC + col] = f2bu(acc[mi][ni][j] + bias);
                }
        }
    } else {
        const int kbase = qbase + wr * 64;
        unsigned short* Zn = Z + (size_t)n * CC * HWD;
#pragma unroll
        for (int ni = 0; ni < 4; ++ni) {
            const int o = n0 + wc * 64 + ni * 16 + lrow;
#pragma unroll
            for (int mi = 0; mi < 4; ++mi) {
                ushort4 v;
                v.x = f2bu(acc[mi][ni][0]);
                v.y = f2bu(acc[mi][ni][1]);
                v.z = f2bu(acc[mi][ni][2]);
                v.w = f2bu(acc[mi][ni][3]);
                *(ushort4*)(Zn + (size_t)o * HWD + kbase + mi * 16 + (hi << 2)) = v;
            }
        }
    }
}

// ---------------- attention: out = x + b + (Z P^T)/rowsum ----------------
// 8 waves, 128-query tile, 4 iters of 256 keys, 256 blocks = 1/CU.
__global__ __launch_bounds__(512, 2) void k_attn8(const unsigned short* __restrict__ tp,
                                                  const unsigned short* __restrict__ Z,
                                                  const float* __restrict__ bfu,
                                                  const float* __restrict__ x,
                                                  float* __restrict__ out) {
    constexpr int QST = 264;
    constexpr int PST = 264;
    constexpr int QSZ = 128 * QST;
    __shared__ __align__(16) unsigned short SL[QSZ + 128 * PST];  // 135,168 B
    __shared__ float rowsum[128];
    unsigned short* Qs = SL;                       // [128][264]
    unsigned short* P  = SL + QSZ;                 // [128][264] (256 keys + pad)

    const int b = blockIdx.x;
    const int n = b & 31;                          // XCD = b%8 = n%8 -> 4 batches/XCD
    const int q0 = (b >> 5) << 7;                  // 8 q-tiles of 128
    const int t = threadIdx.x, lane = t & 63, wave = t >> 6;
    const int lrow = lane & 15, hi = lane >> 4, lhk = hi << 3;
    const f32x4 fz = {0.f, 0.f, 0.f, 0.f};

    const unsigned short* tpn = tp + (size_t)n * HWD * CC;
    const unsigned short* Zn  = Z + (size_t)n * CC * HWD;

    if (t < 128) rowsum[t] = 0.f;
    // stage Q tile: rows q0..q0+127, d 0..255 (coalesced row-major)
#pragma unroll
    for (int pass = 0; pass < 8; ++pass) {
        int chunk = (pass << 9) + t;               // 0..4095
        int row = chunk >> 5, co = (chunk & 31) << 3;
        *(short8*)(Qs + row * QST + co) =
            *(const short8*)(tpn + (size_t)(q0 + row) * CC + co);
    }
    __syncthreads();

    f32x4 accG[8][4];                              // [qj][mi]: row=q, col=o
#pragma unroll
    for (int qj = 0; qj < 8; ++qj)
#pragma unroll
        for (int mi = 0; mi < 4; ++mi) accG[qj][mi] = fz;

    const int kw = wave << 4;                      // wave's 16-key slot per 128-sub
    const int ob = wave << 6;                      // wave's 64-output (o) range

    for (int it = 0; it < 4; ++it) {
        const int kv0 = it << 8;                   // 256-key iter base
        const size_t krow0 = (size_t)(kv0 + kw + lrow) * CC + 256;
        const size_t krow1 = (size_t)(kv0 + 128 + kw + lrow) * CC + 256;
        // ---- S phase: both 128-key subtiles, kfr pair loaded once per kt ----
        f32x4 accA[2][8];
#pragma unroll
        for (int k2 = 0; k2 < 2; ++k2)
#pragma unroll
            for (int qj = 0; qj < 8; ++qj) accA[k2][qj] = fz;
#pragma unroll
        for (int kt = 0; kt < 8; ++kt) {
            const int d0 = (kt << 5) + lhk;
            short8 kf0 = *(const short8*)(tpn + krow0 + d0);
            short8 kf1 = *(const short8*)(tpn + krow1 + d0);
#pragma unroll
            for (int qj = 0; qj < 8; ++qj) {
                short8 qfr = *(const short8*)(Qs + (qj * 16 + lrow) * QST + d0);
                accA[0][qj] = __builtin_amdgcn_mfma_f32_16x16x32_bf16(qfr, kf0, accA[0][qj], 0, 0, 0);
                accA[1][qj] = __builtin_amdgcn_mfma_f32_16x16x32_bf16(qfr, kf1, accA[1][qj], 0, 0, 0);
            }
        }
        // exp -> P, psum -> rowsum
        float psum[8][4];
#pragma unroll
        for (int qj = 0; qj < 8; ++qj)
#pragma unroll
            for (int j = 0; j < 4; ++j) psum[qj][j] = 0.f;
#pragma unroll
        for (int k2 = 0; k2 < 2; ++k2) {
            const int pcol = (k2 << 7) + kw + lrow;
#pragma unroll
            for (int qj = 0; qj < 8; ++qj)
#pragma unroll
                for (int j = 0; j < 4; ++j) {
                    float p = __expf(accA[k2][qj][j] * 0.0625f);
                    psum[qj][j] += p;
                    P[(qj * 16 + hi * 4 + j) * PST + pcol] = f2bu(p);
                }
        }
#pragma unroll
        for (int qj = 0; qj < 8; ++qj)
#pragma unroll
            for (int j = 0; j < 4; ++j) {
                float s = psum[qj][j];
                s += __shfl_xor(s, 1, 16);
                s += __shfl_xor(s, 2, 16);
                s += __shfl_xor(s, 4, 16);
                s += __shfl_xor(s, 8, 16);
                if (lrow == 0) atomicAdd(&rowsum[qj * 16 + hi * 4 + j], s);
            }
        __syncthreads();                           // P complete
        // ---- ZP phase: accG[q][o] += P . Z^T (swapped operands) ----
        __builtin_amdgcn_s_setprio(1);
#pragma unroll
        for (int ks = 0; ks < 8; ++ks) {
            const int kb = (ks << 5) + lhk;
            short8 zf[4];
#pragma unroll
            for (int mi = 0; mi < 4; ++mi)
                zf[mi] = *(const short8*)(Zn + (size_t)(ob + mi * 16 + lrow) * HWD + kv0 + kb);
#pragma unroll
            for (int qj = 0; qj < 8; ++qj) {
                short8 pa = *(const short8*)(P + (qj * 16 + lrow) * PST + kb);
#pragma unroll
                for (int mi = 0; mi < 4; ++mi)
                    accG[qj][mi] = __builtin_amdgcn_mfma_f32_16x16x32_bf16(
                        pa, zf[mi], accG[qj][mi], 0, 0, 0);
            }
        }
        __builtin_amdgcn_s_setprio(0);
        __syncthreads();                           // P consumed; atomics drained
    }

    // ---- epilogue: out[n, o, q] = x + b_fuse[o] + accG / rowsum[q] ----
    if (t < 128) rowsum[t] = 1.f / rowsum[t];
    __syncthreads();
    float bias[4];
#pragma unroll
    for (int mi = 0; mi < 4; ++mi) bias[mi] = bfu[ob + mi * 16 + lrow];
#pragma unroll
    for (int qj = 0; qj < 8; ++qj) {
        const float4 inv4 = *(const float4*)&rowsum[qj * 16 + (hi << 2)];
#pragma unroll
        for (int mi = 0; mi < 4; ++mi) {
            const int o = ob + mi * 16 + lrow;
            const size_t idx = ((size_t)(n * CC + o)) * HWD + q0 + qj * 16 + (hi << 2);
            const float4 xr = *(const float4*)(x + idx);
            float4 r;
            r.x = accG[qj][mi][0] * inv4.x + bias[mi] + xr.x;
            r.y = accG[qj][mi][1] * inv4.y + bias[mi] + xr.y;
            r.z = accG[qj][mi][2] * inv4.z + bias[mi] + xr.z;
            r.w = accG[qj][mi][3] * inv4.w + bias[mi] + xr.w;
            *(float4*)(out + idx) = r;
        }
    }
}

extern "C" void kernel_launch(void* const* d_in, const int* in_sizes, int n_in,
                              void* d_out, int out_size, void* d_ws, size_t ws_size,
                              hipStream_t stream) {
    const float* x  = (const float*)d_in[0];
    const float* Wt = (const float*)d_in[1];
    const float* bt = (const float*)d_in[2];
    const float* Wp = (const float*)d_in[3];
    const float* bp = (const float*)d_in[4];
    const float* Wf = (const float*)d_in[5];
    const float* bfu = (const float*)d_in[6];
    float* out = (float*)d_out;

    char* ws = (char*)d_ws;
    unsigned short* tp    = (unsigned short*)(ws);                 // 32 MB
    unsigned short* Z     = (unsigned short*)(ws + 33554432);      // 32 MB
    unsigned short* Wcat  = (unsigned short*)(ws + 67108864);      // 512 KB
    unsigned short* Wfuse = (unsigned short*)(ws + 67633152);      // 512 KB

    k_packw<<<dim3(1024), 256, 0, stream>>>(Wt, Wp, Wf, Wcat, Wfuse);
    k_mm   <<<dim3(256, 4), 512, 0, stream>>>(x, Wcat, Wfuse, bt, bp, tp, Z);
    k_attn8<<<dim3(256), 512, 0, stream>>>(tp, Z, bfu, x, out);
}